// Round 2
// baseline (18389.439 us; speedup 1.0000x reference)
//
#include <hip/hip_runtime.h>
#include <cstdint>
#include <cstddef>

#define NBATCH 2
#define NSAMPLE 32

// ---------------------------------------------------------------------------
// transpose xyz [B,N,3] -> xyzT [B,3,N]  (stage-0 features)
// ---------------------------------------------------------------------------
__global__ void xyzT_kernel(const float* __restrict__ xyz, float* __restrict__ xyzT, int N)
{
    int t = blockIdx.x * blockDim.x + threadIdx.x;
    int total = NBATCH * N;
    if (t >= total) return;
    int b = t / N, n = t - b * N;
    const float* p = xyz + ((size_t)b * N + n) * 3;
    float* o = xyzT + (size_t)b * 3 * N + n;
    o[0]            = p[0];
    o[(size_t)N]    = p[1];
    o[2 * (size_t)N] = p[2];
}

// ---------------------------------------------------------------------------
// Furthest-point sampling, one-barrier-per-step structure.
// One block per batch; coords + running min-dists live in registers.
// Argmax via packed uint64 key = (float_bits(dist)<<32) | ~index  -> a single
// 64-bit max gives max-dist with lowest-index tie-break (dists >= 0, so the
// float bit pattern is monotone).  Exact jnp rounding: plain mul/add (no fma),
// fminf; argmax first-max semantics via the ~index key.
// Per step: update loop -> in-wave shuffle max -> per-wave key to LDS
// (double-buffered on step parity) -> ONE __syncthreads -> all threads
// combine NW keys -> uniform winner index -> scalar (uniform) reload of the
// winner's coords from global.
// ---------------------------------------------------------------------------
template<int PPT, int BT>
__global__ void fps_kernel(const float* __restrict__ xyz, int npoint,
                           float* __restrict__ query)
{
    const int N = PPT * BT;
    constexpr int NW = BT / 64;
    const int b = blockIdx.x;
    const int t = threadIdx.x;
    const int lane = t & 63;
    const int wid  = t >> 6;
    const float* xb = xyz + (size_t)b * N * 3;

    float px[PPT], py[PPT], pz[PPT], dd[PPT];
#pragma unroll
    for (int i = 0; i < PPT; ++i) {
        int p = i * BT + t;
        px[i] = xb[p * 3 + 0];
        py[i] = xb[p * 3 + 1];
        pz[i] = xb[p * 3 + 2];
        dd[i] = 1e10f;
    }

    __shared__ unsigned long long s_wkey[2][NW];

    float cx = xb[0], cy = xb[1], cz = xb[2];
    if (t == 0) {
        float* q = query + (size_t)b * npoint * 3;
        q[0] = cx; q[1] = cy; q[2] = cz;
    }

    for (int step = 1; step < npoint; ++step) {
        float bd = -1.0f;
        int bslot = 0;
#pragma unroll
        for (int i = 0; i < PPT; ++i) {
            float dx = px[i] - cx, dy = py[i] - cy, dz = pz[i] - cz;
            float d = __fmul_rn(dx, dx);
            d = __fadd_rn(d, __fmul_rn(dy, dy));
            d = __fadd_rn(d, __fmul_rn(dz, dz));
            float nd = fminf(dd[i], d);
            dd[i] = nd;
            bool g = nd > bd;                 // strict > : first-max kept (i ascending)
            bd    = g ? nd : bd;
            bslot = g ? i : bslot;
        }
        int bidx = bslot * BT + t;            // global point index (monotone in bslot)
        unsigned long long key =
            ((unsigned long long)__float_as_uint(bd) << 32) | (unsigned int)(~bidx);
        // in-wave 64-lane max reduce
#pragma unroll
        for (int m = 1; m < 64; m <<= 1) {
            unsigned long long o = __shfl_xor(key, m);
            key = (o > key) ? o : key;
        }
        if (lane == 0) s_wkey[step & 1][wid] = key;
        __syncthreads();
        unsigned long long k = s_wkey[step & 1][0];
#pragma unroll
        for (int w = 1; w < NW; ++w) {
            unsigned long long o = s_wkey[step & 1][w];
            k = (o > k) ? o : k;
        }
        int widx = (int)(~(unsigned int)k);   // block-uniform winner index
        int u = __builtin_amdgcn_readfirstlane(widx);
        const float* wp = xb + (size_t)u * 3;
        cx = wp[0]; cy = wp[1]; cz = wp[2];   // uniform (scalar) load
        if (t == 0) {
            float* q = query + ((size_t)b * npoint + step) * 3;
            q[0] = cx; q[1] = cy; q[2] = cz;
        }
    }
}

// ---------------------------------------------------------------------------
// Ball query: one wave per query point.  First NSAMPLE in-radius support
// indices in ascending order, padded with the first hit.  Exact fp32 rounding
// (no fma) so the d2 < r2 decision matches the reference.
// ---------------------------------------------------------------------------
__global__ void ballquery_kernel(const float* __restrict__ support,
                                 const float* __restrict__ query,
                                 int N, int Q, float r2,
                                 int* __restrict__ nbr)
{
    int gw   = (blockIdx.x * blockDim.x + threadIdx.x) >> 6;
    int lane = threadIdx.x & 63;
    if (gw >= NBATCH * Q) return;
    int b = gw / Q;
    int q = gw - b * Q;

    const float* sb = support + (size_t)b * N * 3;
    const float* qp = query + ((size_t)b * Q + q) * 3;
    float qx = qp[0], qy = qp[1], qz = qp[2];
    int* out = nbr + ((size_t)b * Q + q) * NSAMPLE;

    int cnt = 0, first = 0;
    for (int base = 0; base < N; base += 64) {      // N is a multiple of 64
        int j = base + lane;
        float dx = __fsub_rn(sb[j * 3 + 0], qx);
        float dy = __fsub_rn(sb[j * 3 + 1], qy);
        float dz = __fsub_rn(sb[j * 3 + 2], qz);
        float d2 = __fmul_rn(dx, dx);
        d2 = __fadd_rn(d2, __fmul_rn(dy, dy));
        d2 = __fadd_rn(d2, __fmul_rn(dz, dz));
        bool inr = d2 < r2;
        unsigned long long mask = __ballot(inr);
        if (mask) {
            if (cnt == 0) first = base + (int)__builtin_ctzll(mask);
            if (inr) {
                int pos = cnt + (int)__popcll(mask & ((1ull << lane) - 1ull));
                if (pos < NSAMPLE) out[pos] = j;
            }
            cnt += (int)__popcll(mask);
            if (cnt >= NSAMPLE) break;
        }
    }
    for (int pos = cnt + lane; pos < NSAMPLE; pos += 64) out[pos] = first;  // pad with first hit
}

// ---------------------------------------------------------------------------
// Build F0 [3+C, Q*32] for one batch: rows 0..2 = relative coords dp,
// rows 3.. = gathered previous features.
// ---------------------------------------------------------------------------
__global__ void gather_kernel(const float* __restrict__ support,
                              const float* __restrict__ query,
                              const int* __restrict__ nbr,
                              const float* __restrict__ feats,  // [B,C,N]
                              int N, int Q, int C, int b,
                              float* __restrict__ F0)
{
    int n = blockIdx.x * blockDim.x + threadIdx.x;
    int Nn = Q * NSAMPLE;
    if (n >= Nn) return;
    int q = n >> 5, s = n & 31;
    int j = nbr[((size_t)b * Q + q) * NSAMPLE + s];
    const float* sp = support + ((size_t)b * N + j) * 3;
    const float* qp = query + ((size_t)b * Q + q) * 3;
    size_t NnS = (size_t)Nn;
    F0[n]           = sp[0] - qp[0];
    F0[NnS + n]     = sp[1] - qp[1];
    F0[2 * NnS + n] = sp[2] - qp[2];
    const float* fb = feats + (size_t)b * C * N;
    float* Fo = F0 + 3 * NnS + n;
    for (int c = 0; c < C; ++c) Fo[(size_t)c * NnS] = fb[(size_t)c * N + j];
}

// ---------------------------------------------------------------------------
// fp32 tiled GEMM: Out[M,Nn] = relu(W[M,K] * F[K,Nn] + bias).
// 64x64 tile, BK=16, 256 threads, 4x4 micro-tile per thread.
// POOL=true fuses the max-over-32-neighbors pool: Out becomes [B,M,Nn/32]
// (batch slice b), saving the biggest intermediate write+read.
// ---------------------------------------------------------------------------
template<bool POOL>
__global__ __launch_bounds__(256)
void gemm_relu(const float* __restrict__ W, const float* __restrict__ bias,
               const float* __restrict__ F, float* __restrict__ Out,
               int M, int K, int Nn, int b)
{
    __shared__ float Ws[16][64];
    __shared__ float Fs[16][68];           // +4 pad, rows stay 16B aligned

    const int n0 = blockIdx.x * 64;
    const int m0 = blockIdx.y * 64;
    const int tid = threadIdx.x;
    const int tx = tid & 15, ty = tid >> 4;

    float acc[4][4] = {};

    const int wm = tid >> 2;               // W row within tile
    const int wk = (tid & 3) * 4;          // W k-offset
    const int fk = tid >> 4;               // F row within tile
    const int fn = (tid & 15) * 4;         // F col offset

    for (int k0 = 0; k0 < K; k0 += 16) {
#pragma unroll
        for (int j = 0; j < 4; ++j) {
            int kk = wk + j;
            int kg = k0 + kk;
            Ws[kk][wm] = (kg < K) ? W[(size_t)(m0 + wm) * K + kg] : 0.0f;
        }
        {
            int kg = k0 + fk;
            float4 v = make_float4(0.f, 0.f, 0.f, 0.f);
            if (kg < K) v = *(const float4*)(F + (size_t)kg * Nn + n0 + fn);
            *(float4*)&Fs[fk][fn] = v;
        }
        __syncthreads();
#pragma unroll
        for (int kk = 0; kk < 16; ++kk) {
            float av[4], bv[4];
            *(float4*)av = *(const float4*)&Ws[kk][ty * 4];
            *(float4*)bv = *(const float4*)&Fs[kk][tx * 4];
#pragma unroll
            for (int i = 0; i < 4; ++i)
#pragma unroll
                for (int j = 0; j < 4; ++j)
                    acc[i][j] = fmaf(av[i], bv[j], acc[i][j]);
        }
        __syncthreads();
    }

    if constexpr (!POOL) {
#pragma unroll
        for (int i = 0; i < 4; ++i) {
            int m = m0 + ty * 4 + i;
            float bvs = bias[m];
            float4 r;
            r.x = fmaxf(acc[i][0] + bvs, 0.0f);
            r.y = fmaxf(acc[i][1] + bvs, 0.0f);
            r.z = fmaxf(acc[i][2] + bvs, 0.0f);
            r.w = fmaxf(acc[i][3] + bvs, 0.0f);
            *(float4*)(Out + (size_t)m * Nn + n0 + tx * 4) = r;
        }
    } else {
        __shared__ float Cs[64][65];
#pragma unroll
        for (int i = 0; i < 4; ++i) {
            int mr = ty * 4 + i;
            float bvs = bias[m0 + mr];
#pragma unroll
            for (int j = 0; j < 4; ++j)
                Cs[mr][tx * 4 + j] = fmaxf(acc[i][j] + bvs, 0.0f);
        }
        __syncthreads();
        if (tid < 128) {
            int r = tid >> 1, g = tid & 1;         // row in tile, which 32-group
            float mx = Cs[r][g * 32];
            for (int c = 1; c < 32; ++c) mx = fmaxf(mx, Cs[r][g * 32 + c]);
            int Qn = Nn >> 5;
            Out[((size_t)b * M + m0 + r) * Qn + (n0 >> 5) + g] = mx;
        }
    }
}

// ---------------------------------------------------------------------------
extern "C" void kernel_launch(void* const* d_in, const int* in_sizes, int n_in,
                              void* d_out, int out_size, void* d_ws, size_t ws_size,
                              hipStream_t stream)
{
    (void)in_sizes; (void)n_in; (void)out_size; (void)ws_size;
    const float* xyz = (const float*)d_in[0];
    const float* W[4][3]; const float* Bi[4][3];
    for (int k = 0; k < 4; ++k)
        for (int l = 0; l < 3; ++l) {
            W[k][l]  = (const float*)d_in[1 + k * 6 + l * 2];
            Bi[k][l] = (const float*)d_in[2 + k * 6 + l * 2];
        }
    float* out = (float*)d_out;

    uintptr_t cur = (uintptr_t)d_ws;
    auto alloc = [&](size_t bytes) -> void* {
        void* p = (void*)cur;
        cur += (bytes + 255) & ~(size_t)255;
        return p;
    };
    float* xyzT = (float*)alloc((size_t)NBATCH * 3 * 16384 * sizeof(float));
    float* qA   = (float*)alloc((size_t)NBATCH * 4096 * 3 * sizeof(float));
    float* qB   = (float*)alloc((size_t)NBATCH * 4096 * 3 * sizeof(float));
    int*   nbr  = (int*)  alloc((size_t)NBATCH * 4096 * NSAMPLE * sizeof(int));
    float* f0   = (float*)alloc((size_t)NBATCH * 128 * 4096 * sizeof(float));
    float* f1   = (float*)alloc((size_t)NBATCH * 256 * 1024 * sizeof(float));
    float* f2   = (float*)alloc((size_t)NBATCH * 512 * 256 * sizeof(float));
    // per-batch GEMM ping-pong (max slab = 64*131072 = 8388608 floats)
    float* X = (float*)alloc((size_t)8388608 * sizeof(float));
    float* Y = (float*)alloc((size_t)8388608 * sizeof(float));

    xyzT_kernel<<<(NBATCH * 16384 + 255) / 256, 256, 0, stream>>>(xyz, xyzT, 16384);

    struct StageP { int N, Q, Cprev, c1, c2, c3; double r; };
    const StageP st[4] = {
        {16384, 4096,   3,   64,  64,  128, 0.1},
        { 4096, 1024, 128,  128, 128,  256, 0.2},
        { 1024,  256, 256,  256, 256,  512, 0.4},
        {  256,   64, 512,  512, 512, 1024, 0.8},
    };
    const float* support   = xyz;
    const float* featsPrev = xyzT;
    float* qbuf[2]     = {qA, qB};
    float* featsOut[4] = {f0, f1, f2, out};

    for (int k = 0; k < 4; ++k) {
        const StageP& s = st[k];
        float* qcur = qbuf[k & 1];
        if      (k == 0) fps_kernel<32, 512><<<NBATCH, 512, 0, stream>>>(support, s.Q, qcur);
        else if (k == 1) fps_kernel< 8, 512><<<NBATCH, 512, 0, stream>>>(support, s.Q, qcur);
        else if (k == 2) fps_kernel< 2, 512><<<NBATCH, 512, 0, stream>>>(support, s.Q, qcur);
        else             fps_kernel< 1, 256><<<NBATCH, 256, 0, stream>>>(support, s.Q, qcur);

        float r2 = (float)(s.r * s.r);   // matches jax float32(weak double) boundary
        ballquery_kernel<<<(NBATCH * s.Q) / 4, 256, 0, stream>>>(support, qcur, s.N, s.Q, r2, nbr);

        int K0 = 3 + s.Cprev;
        int Nn = s.Q * NSAMPLE;
        for (int b = 0; b < NBATCH; ++b) {
            gather_kernel<<<(Nn + 255) / 256, 256, 0, stream>>>(
                support, qcur, nbr, featsPrev, s.N, s.Q, s.Cprev, b, X);
            gemm_relu<false><<<dim3(Nn / 64, s.c1 / 64, 1), 256, 0, stream>>>(
                W[k][0], Bi[k][0], X, Y, s.c1, K0, Nn, 0);
            gemm_relu<false><<<dim3(Nn / 64, s.c2 / 64, 1), 256, 0, stream>>>(
                W[k][1], Bi[k][1], Y, X, s.c2, s.c1, Nn, 0);
            gemm_relu<true><<<dim3(Nn / 64, s.c3 / 64, 1), 256, 0, stream>>>(
                W[k][2], Bi[k][2], X, featsOut[k], s.c3, s.c2, Nn, b);
        }
        support   = qcur;
        featsPrev = featsOut[k];
    }
}

// Round 3
// 9333.014 us; speedup vs baseline: 1.9704x; 1.9704x over previous
//
#include <hip/hip_runtime.h>
#include <cstdint>
#include <cstddef>

#define NBATCH 2
#define NSAMPLE 32

// ---------------------------------------------------------------------------
// transpose xyz [B,N,3] -> xyzT [B,3,N]  (stage-0 features)
// ---------------------------------------------------------------------------
__global__ void xyzT_kernel(const float* __restrict__ xyz, float* __restrict__ xyzT, int N)
{
    int t = blockIdx.x * blockDim.x + threadIdx.x;
    int total = NBATCH * N;
    if (t >= total) return;
    int b = t / N, n = t - b * N;
    const float* p = xyz + ((size_t)b * N + n) * 3;
    float* o = xyzT + (size_t)b * 3 * N + n;
    o[0]            = p[0];
    o[(size_t)N]    = p[1];
    o[2 * (size_t)N] = p[2];
}

// ---------------------------------------------------------------------------
// Furthest-point sampling, one-barrier-per-step.
// Coords + running min-dists strictly in registers (launch_bounds sized so
// they FIT -- round-2 spilled them to scratch, the big regression).
// Packed key u64 = (float_bits(dist)<<32) | ~index : single 64-bit max ==
// max-dist with lowest-index tie-break (dists >= 0 -> bits monotone).
// Exact jnp rounding: plain mul/add (no fma), fminf.
// Per step: update -> in-wave butterfly max -> lane0 key to LDS (parity
// double-buffer) -> ONE barrier -> all threads tree-combine NW keys ->
// broadcast global load of winner coords (same addr all lanes = 1 line).
// No dynamic register-array indexing anywhere.
// ---------------------------------------------------------------------------
template<int PPT, int BT, int MINW>
__global__ __launch_bounds__(BT, MINW)
void fps_kernel(const float* __restrict__ xyz, int npoint,
                float* __restrict__ query)
{
    const int N = PPT * BT;
    constexpr int NW = BT / 64;
    const int b = blockIdx.x;
    const int t = threadIdx.x;
    const int lane = t & 63;
    const int wid  = t >> 6;
    const float* xb = xyz + (size_t)b * N * 3;

    float px[PPT], py[PPT], pz[PPT], dd[PPT];
#pragma unroll
    for (int i = 0; i < PPT; ++i) {
        int p = i * BT + t;
        px[i] = xb[p * 3 + 0];
        py[i] = xb[p * 3 + 1];
        pz[i] = xb[p * 3 + 2];
        dd[i] = 1e10f;
    }

    __shared__ unsigned long long s_wkey[2][NW];

    float cx = xb[0], cy = xb[1], cz = xb[2];
    if (t == 0) {
        float* q = query + (size_t)b * npoint * 3;
        q[0] = cx; q[1] = cy; q[2] = cz;
    }

    for (int step = 1; step < npoint; ++step) {
        const int buf = step & 1;
        float bd = -1.0f;
        int bslot = 0;
#pragma unroll
        for (int i = 0; i < PPT; ++i) {
            float dx = px[i] - cx, dy = py[i] - cy, dz = pz[i] - cz;
            float d = __fmul_rn(dx, dx);
            d = __fadd_rn(d, __fmul_rn(dy, dy));
            d = __fadd_rn(d, __fmul_rn(dz, dz));
            float nd = fminf(dd[i], d);
            dd[i] = nd;
            bool g = nd > bd;                 // strict >: first-max kept (i ascending)
            bd    = g ? nd : bd;
            bslot = g ? i : bslot;
        }
        int bidx = bslot * BT + t;            // global point index
        unsigned long long key =
            ((unsigned long long)__float_as_uint(bd) << 32) | (unsigned int)(~bidx);
        // in-wave 64-lane butterfly max
#pragma unroll
        for (int m = 1; m < 64; m <<= 1) {
            unsigned long long o = __shfl_xor(key, m);
            key = (o > key) ? o : key;
        }
        if (lane == 0) s_wkey[buf][wid] = key;
        __syncthreads();
        // all threads tree-combine the NW wave keys (broadcast LDS reads)
        unsigned long long v[NW];
#pragma unroll
        for (int w = 0; w < NW; ++w) v[w] = s_wkey[buf][w];
#pragma unroll
        for (int s = NW / 2; s > 0; s >>= 1)
#pragma unroll
            for (int w = 0; w < NW / 2; ++w)
                if (w < s) v[w] = (v[w + s] > v[w]) ? v[w + s] : v[w];
        unsigned int widx = ~(unsigned int)v[0];   // block winner (uniform)
        const float* wp = xb + (size_t)widx * 3;
        cx = wp[0]; cy = wp[1]; cz = wp[2];        // broadcast load, 1 line
        if (t == 0) {
            float* q = query + ((size_t)b * npoint + step) * 3;
            q[0] = cx; q[1] = cy; q[2] = cz;
        }
    }
}

// ---------------------------------------------------------------------------
// Ball query: one wave per query point.  First NSAMPLE in-radius support
// indices in ascending order, padded with the first hit.  Exact fp32 rounding
// (no fma) so the d2 < r2 decision matches the reference.
// ---------------------------------------------------------------------------
__global__ void ballquery_kernel(const float* __restrict__ support,
                                 const float* __restrict__ query,
                                 int N, int Q, float r2,
                                 int* __restrict__ nbr)
{
    int gw   = (blockIdx.x * blockDim.x + threadIdx.x) >> 6;
    int lane = threadIdx.x & 63;
    if (gw >= NBATCH * Q) return;
    int b = gw / Q;
    int q = gw - b * Q;

    const float* sb = support + (size_t)b * N * 3;
    const float* qp = query + ((size_t)b * Q + q) * 3;
    float qx = qp[0], qy = qp[1], qz = qp[2];
    int* out = nbr + ((size_t)b * Q + q) * NSAMPLE;

    int cnt = 0, first = 0;
    for (int base = 0; base < N; base += 64) {      // N is a multiple of 64
        int j = base + lane;
        float dx = __fsub_rn(sb[j * 3 + 0], qx);
        float dy = __fsub_rn(sb[j * 3 + 1], qy);
        float dz = __fsub_rn(sb[j * 3 + 2], qz);
        float d2 = __fmul_rn(dx, dx);
        d2 = __fadd_rn(d2, __fmul_rn(dy, dy));
        d2 = __fadd_rn(d2, __fmul_rn(dz, dz));
        bool inr = d2 < r2;
        unsigned long long mask = __ballot(inr);
        if (mask) {
            if (cnt == 0) first = base + (int)__builtin_ctzll(mask);
            if (inr) {
                int pos = cnt + (int)__popcll(mask & ((1ull << lane) - 1ull));
                if (pos < NSAMPLE) out[pos] = j;
            }
            cnt += (int)__popcll(mask);
            if (cnt >= NSAMPLE) break;
        }
    }
    for (int pos = cnt + lane; pos < NSAMPLE; pos += 64) out[pos] = first;  // pad with first hit
}

// ---------------------------------------------------------------------------
// Build F0 [3+C, Q*32] for one batch: rows 0..2 = relative coords dp,
// rows 3.. = gathered previous features.
// ---------------------------------------------------------------------------
__global__ void gather_kernel(const float* __restrict__ support,
                              const float* __restrict__ query,
                              const int* __restrict__ nbr,
                              const float* __restrict__ feats,  // [B,C,N]
                              int N, int Q, int C, int b,
                              float* __restrict__ F0)
{
    int n = blockIdx.x * blockDim.x + threadIdx.x;
    int Nn = Q * NSAMPLE;
    if (n >= Nn) return;
    int q = n >> 5, s = n & 31;
    int j = nbr[((size_t)b * Q + q) * NSAMPLE + s];
    const float* sp = support + ((size_t)b * N + j) * 3;
    const float* qp = query + ((size_t)b * Q + q) * 3;
    size_t NnS = (size_t)Nn;
    F0[n]           = sp[0] - qp[0];
    F0[NnS + n]     = sp[1] - qp[1];
    F0[2 * NnS + n] = sp[2] - qp[2];
    const float* fb = feats + (size_t)b * C * N;
    float* Fo = F0 + 3 * NnS + n;
    for (int c = 0; c < C; ++c) Fo[(size_t)c * NnS] = fb[(size_t)c * N + j];
}

// ---------------------------------------------------------------------------
// fp32 tiled GEMM: Out[M,Nn] = relu(W[M,K] * F[K,Nn] + bias).
// 64x64 tile, BK=16, 256 threads, 4x4 micro-tile per thread.
// POOL=true fuses the max-over-32-neighbors pool: Out becomes [B,M,Nn/32]
// (batch slice b), saving the biggest intermediate write+read.
// ---------------------------------------------------------------------------
template<bool POOL>
__global__ __launch_bounds__(256)
void gemm_relu(const float* __restrict__ W, const float* __restrict__ bias,
               const float* __restrict__ F, float* __restrict__ Out,
               int M, int K, int Nn, int b)
{
    __shared__ float Ws[16][64];
    __shared__ float Fs[16][68];           // +4 pad, rows stay 16B aligned

    const int n0 = blockIdx.x * 64;
    const int m0 = blockIdx.y * 64;
    const int tid = threadIdx.x;
    const int tx = tid & 15, ty = tid >> 4;

    float acc[4][4] = {};

    const int wm = tid >> 2;               // W row within tile
    const int wk = (tid & 3) * 4;          // W k-offset
    const int fk = tid >> 4;               // F row within tile
    const int fn = (tid & 15) * 4;         // F col offset

    for (int k0 = 0; k0 < K; k0 += 16) {
#pragma unroll
        for (int j = 0; j < 4; ++j) {
            int kk = wk + j;
            int kg = k0 + kk;
            Ws[kk][wm] = (kg < K) ? W[(size_t)(m0 + wm) * K + kg] : 0.0f;
        }
        {
            int kg = k0 + fk;
            float4 v = make_float4(0.f, 0.f, 0.f, 0.f);
            if (kg < K) v = *(const float4*)(F + (size_t)kg * Nn + n0 + fn);
            *(float4*)&Fs[fk][fn] = v;
        }
        __syncthreads();
#pragma unroll
        for (int kk = 0; kk < 16; ++kk) {
            float av[4], bv[4];
            *(float4*)av = *(const float4*)&Ws[kk][ty * 4];
            *(float4*)bv = *(const float4*)&Fs[kk][tx * 4];
#pragma unroll
            for (int i = 0; i < 4; ++i)
#pragma unroll
                for (int j = 0; j < 4; ++j)
                    acc[i][j] = fmaf(av[i], bv[j], acc[i][j]);
        }
        __syncthreads();
    }

    if constexpr (!POOL) {
#pragma unroll
        for (int i = 0; i < 4; ++i) {
            int m = m0 + ty * 4 + i;
            float bvs = bias[m];
            float4 r;
            r.x = fmaxf(acc[i][0] + bvs, 0.0f);
            r.y = fmaxf(acc[i][1] + bvs, 0.0f);
            r.z = fmaxf(acc[i][2] + bvs, 0.0f);
            r.w = fmaxf(acc[i][3] + bvs, 0.0f);
            *(float4*)(Out + (size_t)m * Nn + n0 + tx * 4) = r;
        }
    } else {
        __shared__ float Cs[64][65];
#pragma unroll
        for (int i = 0; i < 4; ++i) {
            int mr = ty * 4 + i;
            float bvs = bias[m0 + mr];
#pragma unroll
            for (int j = 0; j < 4; ++j)
                Cs[mr][tx * 4 + j] = fmaxf(acc[i][j] + bvs, 0.0f);
        }
        __syncthreads();
        if (tid < 128) {
            int r = tid >> 1, g = tid & 1;         // row in tile, which 32-group
            float mx = Cs[r][g * 32];
            for (int c = 1; c < 32; ++c) mx = fmaxf(mx, Cs[r][g * 32 + c]);
            int Qn = Nn >> 5;
            Out[((size_t)b * M + m0 + r) * Qn + (n0 >> 5) + g] = mx;
        }
    }
}

// ---------------------------------------------------------------------------
extern "C" void kernel_launch(void* const* d_in, const int* in_sizes, int n_in,
                              void* d_out, int out_size, void* d_ws, size_t ws_size,
                              hipStream_t stream)
{
    (void)in_sizes; (void)n_in; (void)out_size; (void)ws_size;
    const float* xyz = (const float*)d_in[0];
    const float* W[4][3]; const float* Bi[4][3];
    for (int k = 0; k < 4; ++k)
        for (int l = 0; l < 3; ++l) {
            W[k][l]  = (const float*)d_in[1 + k * 6 + l * 2];
            Bi[k][l] = (const float*)d_in[2 + k * 6 + l * 2];
        }
    float* out = (float*)d_out;

    uintptr_t cur = (uintptr_t)d_ws;
    auto alloc = [&](size_t bytes) -> void* {
        void* p = (void*)cur;
        cur += (bytes + 255) & ~(size_t)255;
        return p;
    };
    float* xyzT = (float*)alloc((size_t)NBATCH * 3 * 16384 * sizeof(float));
    float* qA   = (float*)alloc((size_t)NBATCH * 4096 * 3 * sizeof(float));
    float* qB   = (float*)alloc((size_t)NBATCH * 4096 * 3 * sizeof(float));
    int*   nbr  = (int*)  alloc((size_t)NBATCH * 4096 * NSAMPLE * sizeof(int));
    float* f0   = (float*)alloc((size_t)NBATCH * 128 * 4096 * sizeof(float));
    float* f1   = (float*)alloc((size_t)NBATCH * 256 * 1024 * sizeof(float));
    float* f2   = (float*)alloc((size_t)NBATCH * 512 * 256 * sizeof(float));
    // per-batch GEMM ping-pong (max slab = 64*131072 = 8388608 floats)
    float* X = (float*)alloc((size_t)8388608 * sizeof(float));
    float* Y = (float*)alloc((size_t)8388608 * sizeof(float));

    xyzT_kernel<<<(NBATCH * 16384 + 255) / 256, 256, 0, stream>>>(xyz, xyzT, 16384);

    struct StageP { int N, Q, Cprev, c1, c2, c3; double r; };
    const StageP st[4] = {
        {16384, 4096,   3,   64,  64,  128, 0.1},
        { 4096, 1024, 128,  128, 128,  256, 0.2},
        { 1024,  256, 256,  256, 256,  512, 0.4},
        {  256,   64, 512,  512, 512, 1024, 0.8},
    };
    const float* support   = xyz;
    const float* featsPrev = xyzT;
    float* qbuf[2]     = {qA, qB};
    float* featsOut[4] = {f0, f1, f2, out};

    for (int k = 0; k < 4; ++k) {
        const StageP& s = st[k];
        float* qcur = qbuf[k & 1];
        // launch_bounds(BT, MINW): MINW=2 on 512-thread blocks -> 256-VGPR
        // budget, register arrays (PPT*4 floats) fit with no scratch spill.
        if      (k == 0) fps_kernel<32, 512, 2><<<NBATCH, 512, 0, stream>>>(support, s.Q, qcur);
        else if (k == 1) fps_kernel< 8, 512, 2><<<NBATCH, 512, 0, stream>>>(support, s.Q, qcur);
        else if (k == 2) fps_kernel< 2, 512, 2><<<NBATCH, 512, 0, stream>>>(support, s.Q, qcur);
        else             fps_kernel< 1, 256, 1><<<NBATCH, 256, 0, stream>>>(support, s.Q, qcur);

        float r2 = (float)(s.r * s.r);   // matches jax float32(weak double) boundary
        ballquery_kernel<<<(NBATCH * s.Q) / 4, 256, 0, stream>>>(support, qcur, s.N, s.Q, r2, nbr);

        int K0 = 3 + s.Cprev;
        int Nn = s.Q * NSAMPLE;
        for (int b = 0; b < NBATCH; ++b) {
            gather_kernel<<<(Nn + 255) / 256, 256, 0, stream>>>(
                support, qcur, nbr, featsPrev, s.N, s.Q, s.Cprev, b, X);
            gemm_relu<false><<<dim3(Nn / 64, s.c1 / 64, 1), 256, 0, stream>>>(
                W[k][0], Bi[k][0], X, Y, s.c1, K0, Nn, 0);
            gemm_relu<false><<<dim3(Nn / 64, s.c2 / 64, 1), 256, 0, stream>>>(
                W[k][1], Bi[k][1], Y, X, s.c2, s.c1, Nn, 0);
            gemm_relu<true><<<dim3(Nn / 64, s.c3 / 64, 1), 256, 0, stream>>>(
                W[k][2], Bi[k][2], X, featsOut[k], s.c3, s.c2, Nn, b);
        }
        support   = qcur;
        featsPrev = featsOut[k];
    }
}